// Round 19
// baseline (112.136 us; speedup 1.0000x reference)
//
#include <hip/hip_runtime.h>
#include <hip/hip_bf16.h>
#include <hip/hip_fp8.h>
#include <stdint.h>

#define Rdim 1023
#define BFR  4190208           // 64*64*1023

typedef float  f32x4  __attribute__((ext_vector_type(4)));
typedef float  f32x4u __attribute__((ext_vector_type(4), aligned(4)));

__device__ __forceinline__ void async16(const void* g, void* l) {
    __builtin_amdgcn_global_load_lds(
        (const __attribute__((address_space(1))) void*)g,
        (__attribute__((address_space(3))) void*)l, 16, 0, 0);
}

#define BAR()  do { __builtin_amdgcn_s_barrier(); __builtin_amdgcn_sched_barrier(0); } while(0)

__device__ __forceinline__ uint32_t f2fp8(float f) {
    __hip_fp8_e4m3 v(f);
    return (uint32_t)v.__x;
}
__device__ __forceinline__ uint32_t pack4(const float* a, float s) {
    return f2fp8(s*a[0]) | (f2fp8(s*a[1])<<8) | (f2fp8(s*a[2])<<16) | (f2fp8(s*a[3])<<24);
}

// ---------------------------------------------------------------------------
// Prep (r18 verbatim — frozen; ~53.5 us). fp8 e4m3; args unscaled, D/E x16.
// Swizzle: 16B chunk c=(r>>4)&3 of row m stored at c^((m>>1)&3) within its
// 64B window (position-independent -> the cons K-split needs no prep change).
// ---------------------------------------------------------------------------
__global__ __launch_bounds__(256) void k_prep(
    const float* __restrict__ x,
    const float* __restrict__ w0, const float* __restrict__ w1,
    const float* __restrict__ w2, const float* __restrict__ w3,
    const float* __restrict__ Dl, const float* __restrict__ Dr,
    const float* __restrict__ El, const float* __restrict__ Er,
    uint8_t* __restrict__ args8, uint8_t* __restrict__ dpad8,
    float* __restrict__ out)
{
    const int blk = blockIdx.x;
    const int t   = threadIdx.x;

    if (blk < 1024) {
        const int id = blk*256 + t;              // 0..262143
        const float* src; int n, c16, r0; size_t dst; int stride;
        if (id < 131072) {
            const int mat = id >> 16;            // 0=Dl 1=Dr
            src = mat ? Dr : Dl;
            const int rem = id & 65535;
            n = rem >> 6; c16 = rem & 63; r0 = c16*16; stride = 1024;
            dst = (mat ? 1048576u : 0u);
        } else {
            const int rem = id - 131072;
            n = rem >> 7; c16 = rem & 127;
            r0 = (c16 & 63)*16; stride = 2048;
            src = (c16 < 64) ? El : Er;
            dst = 2097152u;
        }
        const int pos = ((c16 >> 2) << 6) + (((c16 & 3) ^ ((n >> 1) & 3)) << 4);
        float v[16] = {};
        if (n < Rdim) {
            const float* sp = src + (size_t)n*Rdim + r0;
            if (r0 <= Rdim - 16) {
#pragma unroll
                for (int j = 0; j < 4; ++j) {
                    f32x4u u = *(const f32x4u*)(sp + j*4);
#pragma unroll
                    for (int q = 0; q < 4; ++q) v[j*4+q] = u[q];
                }
            } else {                              // r0 = 1008: 15 valid
#pragma unroll
                for (int j = 0; j < 3; ++j) {
                    f32x4u u = *(const f32x4u*)(sp + j*4);
#pragma unroll
                    for (int q = 0; q < 4; ++q) v[j*4+q] = u[q];
                }
                v[12] = sp[12]; v[13] = sp[13]; v[14] = sp[14];  // r=1023 pad
            }
        }
        uint32_t w[4];
#pragma unroll
        for (int j = 0; j < 4; ++j) w[j] = pack4(v + j*4, 16.f);
        *(uint4*)(dpad8 + dst + (size_t)n*stride + pos) =
            make_uint4(w[0], w[1], w[2], w[3]);
    } else if (blk < 5120) {
        const int m = blk - 1024;
        const int b = m >> 6;
        float wr0[16], wr1[16], wr2[16], wr3[16];
#pragma unroll
        for (int l = 0; l < 16; ++l) {
            wr0[l] = w0[b*16 + l]; wr1[l] = w1[b*16 + l];
            wr2[l] = w2[b*16 + l]; wr3[l] = w3[b*16 + l];
        }
        const float* xb = x + ((size_t)(b*16)*64 + (m & 63)) * (size_t)Rdim;
        float a0[4] = {}, a1[4] = {}, a2[4] = {}, a3[4] = {};
        if (t < 255) {
#pragma unroll
            for (int l = 0; l < 16; ++l) {
                f32x4u v = *(const f32x4u*)(xb + (size_t)l*(64*(size_t)Rdim) + t*4);
#pragma unroll
                for (int j = 0; j < 4; ++j) {
                    a0[j] += wr0[l]*v[j]; a1[j] += wr1[l]*v[j];
                    a2[j] += wr2[l]*v[j]; a3[j] += wr3[l]*v[j];
                }
            }
        } else {
#pragma unroll
            for (int l = 0; l < 16; ++l) {
                const float* p = xb + (size_t)l*(64*(size_t)Rdim) + 1020;
#pragma unroll
                for (int j = 0; j < 3; ++j) {
                    float v = p[j];
                    a0[j] += wr0[l]*v; a1[j] += wr1[l]*v;
                    a2[j] += wr2[l]*v; a3[j] += wr3[l]*v;
                }
            }
        }
        const int r0  = t*4;
        const int S2  = (m >> 1) & 3;
        const int pos = ((r0 >> 6) << 6) + ((((r0 >> 4) & 3) ^ S2) << 4) + (r0 & 15);
        *(uint32_t*)(args8 +            (size_t)m*1024 + pos) = pack4(a0, 1.f);
        *(uint32_t*)(args8 + 4194304 +  (size_t)m*1024 + pos) = pack4(a1, 1.f);
        uint8_t* c12 = args8 + 8388608 + (size_t)m*2048;
        *(uint32_t*)(c12 + pos)        = pack4(a2, 1.f);
        *(uint32_t*)(c12 + 1024 + pos) = pack4(a3, 1.f);
    } else {
        const int k = t >> 6, b2 = t & 63;
        const float* w = (k==0) ? w0 : (k==1) ? w1 : (k==2) ? w2 : w3;
        float s = 0.f, mx = -1e30f;
#pragma unroll
        for (int l = 0; l < 16; ++l) {
            float p = w[b2*16 + l];
            s += p * logf(p + 1e-12f);
            mx = fmaxf(mx, p);
        }
        out[3*(size_t)BFR +       k*64 + b2] = -s / logf(16.f);
        out[3*(size_t)BFR + 256 + k*64 + b2] = mx;
    }
}

// ---------------------------------------------------------------------------
// GEMM — r18 fp8 skeleton, ALL blocks uniform: BM=256, NKT=16, MI=8
// (the r18 post-mortem: cons at BM=128/NKT=32 paid the ~2000-cyc per-kt
// convoy overhead 32x with half the MFMA -> set the 36.7 us makespan;
// car finished in ~18 and idled). cons is K-split: cons1 = c1 x E_l
// (writes out + root term), cons2 = c2 x E_r (writes P; merged after).
// 256 identical blocks, 96 KiB LDS, 1 barrier/kt, counted vmcnt(4).
// EPI: 0 = plain store, 1 = + root_filler x root_role.
// ---------------------------------------------------------------------------
template<int AstB, int EPI>
__device__ __forceinline__ void gemm_t(
    const uint8_t* __restrict__ Ab, const uint8_t* __restrict__ Bb,
    const float* __restrict__ rf, const float* __restrict__ rr,
    float* __restrict__ outp, char* lds, int mt, int nt)
{
    constexpr int MI   = 8;
    constexpr int ABUF = 16384;

    const int tid  = threadIdx.x;
    const int wave = tid >> 6, lane = tid & 63;
    const int wm   = wave >> 2, wn = wave & 3; // 2M x 4N
    const int lr   = lane & 15, lk = lane >> 4;
    const int sw   = (lr >> 1) & 3;
    const int cb0 = ((((lk >> 1)    ) ^ sw) << 4) + ((lk & 1) << 3);
    const int cb1 = (((2 + (lk >> 1)) ^ sw) << 4) + ((lk & 1) << 3);

    const uint8_t* AgT = Ab + (size_t)(mt*256 + (tid>>2))*AstB + (tid&3)*16;
    const uint8_t* BgT = Bb + (size_t)(nt*256 + (tid>>2))*AstB + (tid&3)*16;

    f32x4 acc[MI][4] = {};
    long af[MI][2], bfr[4][2];

#define STG(bufidx, kt) do {                                                  \
    char* _a = lds + (bufidx)*ABUF + wave*1024;                               \
    char* _b = lds + 49152 + (bufidx)*16384 + wave*1024;                      \
    const size_t _ko = (size_t)(kt)*64;                                       \
    _Pragma("unroll") for (int i = 0; i < 2; ++i)                             \
        async16(AgT + (size_t)(i*128)*AstB + _ko, _a + i*8192);               \
    _Pragma("unroll") for (int i = 0; i < 2; ++i)                             \
        async16(BgT + (size_t)(i*128)*AstB + _ko, _b + i*8192);               \
} while(0)

    STG(0, 0); STG(1, 1);
    asm volatile("s_waitcnt vmcnt(4)" ::: "memory");
    BAR();

    int cb = 0;
    for (int kt = 0; kt < 16; ++kt) {
        char* cA = lds + cb*ABUF;
        char* cB = lds + 49152 + cb*16384;
        int sb = cb + 2; if (sb >= 3) sb -= 3;
        const bool st = (kt + 2 < 16);
#pragma unroll
        for (int mi = 0; mi < MI; ++mi) {
            const char* rp = cA + (wm*128 + mi*16 + lr)*64;
            af[mi][0] = *(const long*)(rp + cb0);
            af[mi][1] = *(const long*)(rp + cb1);
        }
#pragma unroll
        for (int j = 0; j < 4; ++j) {
            const char* rp = cB + (wn*64 + j*16 + lr)*64;
            bfr[j][0] = *(const long*)(rp + cb0);
            bfr[j][1] = *(const long*)(rp + cb1);
        }
        if (st) STG(sb, kt+2);
        __builtin_amdgcn_s_setprio(1);
#pragma unroll
        for (int ks = 0; ks < 2; ++ks)
#pragma unroll
        for (int mi = 0; mi < MI; ++mi)
#pragma unroll
        for (int j = 0; j < 4; ++j)
            acc[mi][j] = __builtin_amdgcn_mfma_f32_16x16x32_fp8_fp8(
                af[mi][ks], bfr[j][ks], acc[mi][j], 0, 0, 0);
        __builtin_amdgcn_s_setprio(0);
        if (st)           { asm volatile("s_waitcnt vmcnt(4)" ::: "memory"); }
        else if (kt == 14){ asm volatile("s_waitcnt vmcnt(0)" ::: "memory"); }
        BAR();
        cb = cb + 1; if (cb == 3) cb = 0;
    }
#undef STG

    // epilogue: 16x16 C/D: col = lane&15, row = (lane>>4)*4 + q; undo x16
#pragma unroll
    for (int mi = 0; mi < MI; ++mi) {
        const int gm0 = mt*256 + wm*128 + mi*16 + lk*4;
#pragma unroll
        for (int j = 0; j < 4; ++j) {
            const int gn = nt*256 + wn*64 + j*16 + lr;
            if (gn < Rdim) {
                const float rv = (EPI == 1) ? rr[gn] : 0.f;
#pragma unroll
                for (int q = 0; q < 4; ++q) {
                    float v = acc[mi][j][q] * 0.0625f;
                    if (EPI == 1) v += rf[gm0 + q] * rv;
                    outp[(size_t)(gm0 + q)*Rdim + gn] = v;
                }
            }
        }
    }
}

// 256 uniform blocks: per XCD 8 car + 8 cdr + 8 cons1 + 8 cons2.
__global__ __launch_bounds__(512, 1) void k_gemm(
    const uint8_t* __restrict__ args8, const uint8_t* __restrict__ dpad8,
    const float* __restrict__ root_filler, const float* __restrict__ root_role,
    float* __restrict__ out, float* __restrict__ P)
{
    __shared__ char lds[98304];       // 96 KiB
    const int bid = blockIdx.x;
    const int xcd = bid & 7, idx = bid >> 3;   // idx 0..31
    const int job = idx >> 3;                  // 0 car, 1 cdr, 2 cons1, 3 cons2
    const int tile = xcd*8 + (idx & 7);        // 0..63: mt 0..15, nt 0..3
    const int mt = tile >> 2, nt = tile & 3;

    if (job == 0)
        gemm_t<1024, 0>(args8, dpad8,
            root_filler, root_role, out, lds, mt, nt);
    else if (job == 1)
        gemm_t<1024, 0>(args8 + 4194304, dpad8 + 1048576,
            root_filler, root_role, out + (size_t)BFR, lds, mt, nt);
    else if (job == 2)
        gemm_t<2048, 1>(args8 + 8388608, dpad8 + 2097152,
            root_filler, root_role, out + 2*(size_t)BFR, lds, mt, nt);
    else
        gemm_t<2048, 0>(args8 + 8388608 + 1024, dpad8 + 2097152 + 1024,
            root_filler, root_role, P, lds, mt, nt);
}

// ---------------------------------------------------------------------------
// merge: out_cons += P (1,047,552 float4), bounds-guarded.
// ---------------------------------------------------------------------------
__global__ __launch_bounds__(256) void k_merge(
    const float* __restrict__ P, float* __restrict__ out)
{
    const int i = blockIdx.x*256 + threadIdx.x;
    float* o = out + 2*(size_t)BFR;
#pragma unroll
    for (int r = 0; r < 4; ++r) {
        const int v = i + r*262144;
        if (v < 1047552) {
            f32x4 a = *(const f32x4*)(o + (size_t)v*4);
            f32x4 b = *(const f32x4*)(P + (size_t)v*4);
            a = a + b;
            *(f32x4*)(o + (size_t)v*4) = a;
        }
    }
}

// ---------------------------------------------------------------------------
extern "C" void kernel_launch(void* const* d_in, const int* in_sizes, int n_in,
                              void* d_out, int out_size, void* d_ws, size_t ws_size,
                              hipStream_t stream)
{
    const float* x           = (const float*)d_in[0];
    const float* car_w       = (const float*)d_in[1];
    const float* cdr_w       = (const float*)d_in[2];
    const float* cons1_w     = (const float*)d_in[3];
    const float* cons2_w     = (const float*)d_in[4];
    const float* root_filler = (const float*)d_in[5];
    const float* Dl          = (const float*)d_in[6];
    const float* Dr          = (const float*)d_in[7];
    const float* El          = (const float*)d_in[8];
    const float* Er          = (const float*)d_in[9];
    const float* root_role   = (const float*)d_in[10];
    float* out = (float*)d_out;

    uint8_t* args8 = (uint8_t*)d_ws;                       // 16.8 MB
    uint8_t* dpad8 = args8 + 16777216;                     //  4.2 MB
    float*   P     = (float*)((char*)d_ws + 20971520);     // 16.8 MB fp32

    k_prep <<<dim3(5121), dim3(256), 0, stream>>>(
        x, car_w, cdr_w, cons1_w, cons2_w, Dl, Dr, El, Er, args8, dpad8, out);
    k_gemm <<<dim3(256),  dim3(512), 0, stream>>>(
        args8, dpad8, root_filler, root_role, out, P);
    k_merge<<<dim3(1024), dim3(256), 0, stream>>>(P, out);
}

// Round 20
// 103.974 us; speedup vs baseline: 1.0785x; 1.0785x over previous
//
#include <hip/hip_runtime.h>
#include <hip/hip_bf16.h>
#include <hip/hip_fp8.h>
#include <stdint.h>

#define Rdim 1023
#define BFR  4190208           // 64*64*1023

typedef float  f32x4  __attribute__((ext_vector_type(4)));
typedef float  f32x4u __attribute__((ext_vector_type(4), aligned(4)));

__device__ __forceinline__ void async16(const void* g, void* l) {
    __builtin_amdgcn_global_load_lds(
        (const __attribute__((address_space(1))) void*)g,
        (__attribute__((address_space(3))) void*)l, 16, 0, 0);
}

#define BAR()  do { __builtin_amdgcn_s_barrier(); __builtin_amdgcn_sched_barrier(0); } while(0)

__device__ __forceinline__ uint32_t f2fp8(float f) {
    __hip_fp8_e4m3 v(f);
    return (uint32_t)v.__x;
}
__device__ __forceinline__ uint32_t pack4(const float* a, float s) {
    return f2fp8(s*a[0]) | (f2fp8(s*a[1])<<8) | (f2fp8(s*a[2])<<16) | (f2fp8(s*a[3])<<24);
}

// ---------------------------------------------------------------------------
// Prep (r18 verbatim — frozen). fp8 e4m3; args unscaled, D/E x16 (epilogue
// undoes via 1/16). Swizzle: 16B chunk c=(r>>4)&3 of row m stored at
// c^((m>>1)&3) within its 64B window (position-independent).
// ---------------------------------------------------------------------------
__global__ __launch_bounds__(256) void k_prep(
    const float* __restrict__ x,
    const float* __restrict__ w0, const float* __restrict__ w1,
    const float* __restrict__ w2, const float* __restrict__ w3,
    const float* __restrict__ Dl, const float* __restrict__ Dr,
    const float* __restrict__ El, const float* __restrict__ Er,
    uint8_t* __restrict__ args8, uint8_t* __restrict__ dpad8,
    float* __restrict__ out)
{
    const int blk = blockIdx.x;
    const int t   = threadIdx.x;

    if (blk < 1024) {
        const int id = blk*256 + t;              // 0..262143
        const float* src; int n, c16, r0; size_t dst; int stride;
        if (id < 131072) {
            const int mat = id >> 16;            // 0=Dl 1=Dr
            src = mat ? Dr : Dl;
            const int rem = id & 65535;
            n = rem >> 6; c16 = rem & 63; r0 = c16*16; stride = 1024;
            dst = (mat ? 1048576u : 0u);
        } else {
            const int rem = id - 131072;
            n = rem >> 7; c16 = rem & 127;
            r0 = (c16 & 63)*16; stride = 2048;
            src = (c16 < 64) ? El : Er;
            dst = 2097152u;
        }
        const int pos = ((c16 >> 2) << 6) + (((c16 & 3) ^ ((n >> 1) & 3)) << 4);
        float v[16] = {};
        if (n < Rdim) {
            const float* sp = src + (size_t)n*Rdim + r0;
            if (r0 <= Rdim - 16) {
#pragma unroll
                for (int j = 0; j < 4; ++j) {
                    f32x4u u = *(const f32x4u*)(sp + j*4);
#pragma unroll
                    for (int q = 0; q < 4; ++q) v[j*4+q] = u[q];
                }
            } else {                              // r0 = 1008: 15 valid
#pragma unroll
                for (int j = 0; j < 3; ++j) {
                    f32x4u u = *(const f32x4u*)(sp + j*4);
#pragma unroll
                    for (int q = 0; q < 4; ++q) v[j*4+q] = u[q];
                }
                v[12] = sp[12]; v[13] = sp[13]; v[14] = sp[14];  // r=1023 pad
            }
        }
        uint32_t w[4];
#pragma unroll
        for (int j = 0; j < 4; ++j) w[j] = pack4(v + j*4, 16.f);
        *(uint4*)(dpad8 + dst + (size_t)n*stride + pos) =
            make_uint4(w[0], w[1], w[2], w[3]);
    } else if (blk < 5120) {
        const int m = blk - 1024;
        const int b = m >> 6;
        float wr0[16], wr1[16], wr2[16], wr3[16];
#pragma unroll
        for (int l = 0; l < 16; ++l) {
            wr0[l] = w0[b*16 + l]; wr1[l] = w1[b*16 + l];
            wr2[l] = w2[b*16 + l]; wr3[l] = w3[b*16 + l];
        }
        const float* xb = x + ((size_t)(b*16)*64 + (m & 63)) * (size_t)Rdim;
        float a0[4] = {}, a1[4] = {}, a2[4] = {}, a3[4] = {};
        if (t < 255) {
#pragma unroll
            for (int l = 0; l < 16; ++l) {
                f32x4u v = *(const f32x4u*)(xb + (size_t)l*(64*(size_t)Rdim) + t*4);
#pragma unroll
                for (int j = 0; j < 4; ++j) {
                    a0[j] += wr0[l]*v[j]; a1[j] += wr1[l]*v[j];
                    a2[j] += wr2[l]*v[j]; a3[j] += wr3[l]*v[j];
                }
            }
        } else {
#pragma unroll
            for (int l = 0; l < 16; ++l) {
                const float* p = xb + (size_t)l*(64*(size_t)Rdim) + 1020;
#pragma unroll
                for (int j = 0; j < 3; ++j) {
                    float v = p[j];
                    a0[j] += wr0[l]*v; a1[j] += wr1[l]*v;
                    a2[j] += wr2[l]*v; a3[j] += wr3[l]*v;
                }
            }
        }
        const int r0  = t*4;
        const int S2  = (m >> 1) & 3;
        const int pos = ((r0 >> 6) << 6) + ((((r0 >> 4) & 3) ^ S2) << 4) + (r0 & 15);
        *(uint32_t*)(args8 +            (size_t)m*1024 + pos) = pack4(a0, 1.f);
        *(uint32_t*)(args8 + 4194304 +  (size_t)m*1024 + pos) = pack4(a1, 1.f);
        uint8_t* c12 = args8 + 8388608 + (size_t)m*2048;
        *(uint32_t*)(c12 + pos)        = pack4(a2, 1.f);
        *(uint32_t*)(c12 + 1024 + pos) = pack4(a3, 1.f);
    } else {
        const int k = t >> 6, b2 = t & 63;
        const float* w = (k==0) ? w0 : (k==1) ? w1 : (k==2) ? w2 : w3;
        float s = 0.f, mx = -1e30f;
#pragma unroll
        for (int l = 0; l < 16; ++l) {
            float p = w[b2*16 + l];
            s += p * logf(p + 1e-12f);
            mx = fmaxf(mx, p);
        }
        out[3*(size_t)BFR +       k*64 + b2] = -s / logf(16.f);
        out[3*(size_t)BFR + 256 + k*64 + b2] = mx;
    }
}

// ---------------------------------------------------------------------------
// GEMM — r18 fp8 skeleton; cons uniformized by N-SPLIT (no merge): cons
// tiles BM=256 x BN=128, full K=2048 (NKT=32, JN=2) — per-block FLOPs equal
// to car/cdr (BM=256 x BN=256, K=1024, NKT=16, JN=4). 256 identical-FLOP
// blocks, disjoint outputs. Traffic identical to r18 (cons A x2, B /2).
// BK=64 fp8, triple-buffered 96 KiB LDS, 1 barrier/kt, counted vmcnt(U),
// U = 2 + JN/2. Epilogue x(1/16); EPI=1 adds root_filler x root_role.
// ---------------------------------------------------------------------------
template<int AstB, int NKT, int JN, int EPI>
__device__ __forceinline__ void gemm_t(
    const uint8_t* __restrict__ Ab, const uint8_t* __restrict__ Bb,
    const float* __restrict__ rf, const float* __restrict__ rr,
    float* __restrict__ outp, char* lds, int mt, int nt)
{
    constexpr int MI   = 8;
    constexpr int ABUF = 16384;
    constexpr int U    = 2 + JN/2;             // async16 units per K-tile

    const int tid  = threadIdx.x;
    const int wave = tid >> 6, lane = tid & 63;
    const int wm   = wave >> 2, wn = wave & 3; // 2M x 4N
    const int lr   = lane & 15, lk = lane >> 4;
    const int sw   = (lr >> 1) & 3;
    const int cb0 = ((((lk >> 1)    ) ^ sw) << 4) + ((lk & 1) << 3);
    const int cb1 = (((2 + (lk >> 1)) ^ sw) << 4) + ((lk & 1) << 3);

    const uint8_t* AgT = Ab + (size_t)(mt*256     + (tid>>2))*AstB + (tid&3)*16;
    const uint8_t* BgT = Bb + (size_t)(nt*(JN*64) + (tid>>2))*AstB + (tid&3)*16;

    f32x4 acc[MI][JN] = {};
    long af[MI][2], bfr[JN][2];

#define STG(bufidx, kt) do {                                                  \
    char* _a = lds + (bufidx)*ABUF + wave*1024;                               \
    char* _b = lds + 49152 + (bufidx)*16384 + wave*1024;                      \
    const size_t _ko = (size_t)(kt)*64;                                       \
    _Pragma("unroll") for (int i = 0; i < 2; ++i)                             \
        async16(AgT + (size_t)(i*128)*AstB + _ko, _a + i*8192);               \
    _Pragma("unroll") for (int i = 0; i < JN/2; ++i)                          \
        async16(BgT + (size_t)(i*128)*AstB + _ko, _b + i*8192);               \
} while(0)

    STG(0, 0); STG(1, 1);
    asm volatile("s_waitcnt vmcnt(%0)" :: "n"(U) : "memory");
    BAR();

    int cb = 0;
    for (int kt = 0; kt < NKT; ++kt) {
        char* cA = lds + cb*ABUF;
        char* cB = lds + 49152 + cb*16384;
        int sb = cb + 2; if (sb >= 3) sb -= 3;
        const bool st = (kt + 2 < NKT);
#pragma unroll
        for (int mi = 0; mi < MI; ++mi) {
            const char* rp = cA + (wm*128 + mi*16 + lr)*64;
            af[mi][0] = *(const long*)(rp + cb0);
            af[mi][1] = *(const long*)(rp + cb1);
        }
#pragma unroll
        for (int j = 0; j < JN; ++j) {
            const char* rp = cB + (wn*(JN*16) + j*16 + lr)*64;
            bfr[j][0] = *(const long*)(rp + cb0);
            bfr[j][1] = *(const long*)(rp + cb1);
        }
        if (st) STG(sb, kt+2);
        __builtin_amdgcn_s_setprio(1);
#pragma unroll
        for (int ks = 0; ks < 2; ++ks)
#pragma unroll
        for (int mi = 0; mi < MI; ++mi)
#pragma unroll
        for (int j = 0; j < JN; ++j)
            acc[mi][j] = __builtin_amdgcn_mfma_f32_16x16x32_fp8_fp8(
                af[mi][ks], bfr[j][ks], acc[mi][j], 0, 0, 0);
        __builtin_amdgcn_s_setprio(0);
        if (st)                { asm volatile("s_waitcnt vmcnt(%0)" :: "n"(U) : "memory"); }
        else if (kt == NKT-2)  { asm volatile("s_waitcnt vmcnt(0)" ::: "memory"); }
        BAR();
        cb = cb + 1; if (cb == 3) cb = 0;
    }
#undef STG

    // epilogue: 16x16 C/D: col = lane&15, row = (lane>>4)*4 + q; undo x16
#pragma unroll
    for (int mi = 0; mi < MI; ++mi) {
        const int gm0 = mt*256 + wm*128 + mi*16 + lk*4;
#pragma unroll
        for (int j = 0; j < JN; ++j) {
            const int gn = nt*(JN*64) + wn*(JN*16) + j*16 + lr;
            if (gn < Rdim) {
                const float rv = (EPI == 1) ? rr[gn] : 0.f;
#pragma unroll
                for (int q = 0; q < 4; ++q) {
                    float v = acc[mi][j][q] * 0.0625f;
                    if (EPI == 1) v += rf[gm0 + q] * rv;
                    outp[(size_t)(gm0 + q)*Rdim + gn] = v;
                }
            }
        }
    }
}

// 256 uniform-FLOP blocks: per XCD 16 cons (256x128, K=2048, FIRST) +
// 8 car + 8 cdr (256x256, K=1024).
__global__ __launch_bounds__(512, 1) void k_gemm(
    const uint8_t* __restrict__ args8, const uint8_t* __restrict__ dpad8,
    const float* __restrict__ root_filler, const float* __restrict__ root_role,
    float* __restrict__ out)
{
    __shared__ char lds[98304];       // 96 KiB
    const int bid = blockIdx.x;
    const int xcd = bid & 7, idx = bid >> 3;   // idx 0..31

    if (idx < 16) {
        const int tile = xcd*16 + idx;         // 0..127: mt 0..15, nt 0..7
        gemm_t<2048, 32, 2, 1>(args8 + 8388608, dpad8 + 2097152,
            root_filler, root_role, out + 2*(size_t)BFR, lds, tile >> 3, tile & 7);
    } else if (idx < 24) {
        const int tile = xcd*8 + idx - 16;     // 0..63: mt 0..15, nt 0..3
        gemm_t<1024, 16, 4, 0>(args8, dpad8,
            root_filler, root_role, out, lds, tile >> 2, tile & 3);
    } else {
        const int tile = xcd*8 + idx - 24;
        gemm_t<1024, 16, 4, 0>(args8 + 4194304, dpad8 + 1048576,
            root_filler, root_role, out + (size_t)BFR, lds, tile >> 2, tile & 3);
    }
}

// ---------------------------------------------------------------------------
extern "C" void kernel_launch(void* const* d_in, const int* in_sizes, int n_in,
                              void* d_out, int out_size, void* d_ws, size_t ws_size,
                              hipStream_t stream)
{
    const float* x           = (const float*)d_in[0];
    const float* car_w       = (const float*)d_in[1];
    const float* cdr_w       = (const float*)d_in[2];
    const float* cons1_w     = (const float*)d_in[3];
    const float* cons2_w     = (const float*)d_in[4];
    const float* root_filler = (const float*)d_in[5];
    const float* Dl          = (const float*)d_in[6];
    const float* Dr          = (const float*)d_in[7];
    const float* El          = (const float*)d_in[8];
    const float* Er          = (const float*)d_in[9];
    const float* root_role   = (const float*)d_in[10];
    float* out = (float*)d_out;

    uint8_t* args8 = (uint8_t*)d_ws;              // 16.8 MB
    uint8_t* dpad8 = args8 + 16777216;            //  4.2 MB

    k_prep<<<dim3(5121), dim3(256), 0, stream>>>(
        x, car_w, cdr_w, cons1_w, cons2_w, Dl, Dr, El, Er, args8, dpad8, out);
    k_gemm<<<dim3(256),  dim3(512), 0, stream>>>(
        args8, dpad8, root_filler, root_role, out);
}

// Round 21
// 100.769 us; speedup vs baseline: 1.1128x; 1.0318x over previous
//
#include <hip/hip_runtime.h>
#include <hip/hip_bf16.h>
#include <hip/hip_fp8.h>
#include <stdint.h>

#define Rdim 1023
#define BFR  4190208           // 64*64*1023

typedef float  f32x4  __attribute__((ext_vector_type(4)));
typedef float  f32x4u __attribute__((ext_vector_type(4), aligned(4)));

__device__ __forceinline__ void async16(const void* g, void* l) {
    __builtin_amdgcn_global_load_lds(
        (const __attribute__((address_space(1))) void*)g,
        (__attribute__((address_space(3))) void*)l, 16, 0, 0);
}

#define BAR()  do { __builtin_amdgcn_s_barrier(); __builtin_amdgcn_sched_barrier(0); } while(0)

__device__ __forceinline__ uint32_t f2fp8(float f) {
    __hip_fp8_e4m3 v(f);
    return (uint32_t)v.__x;
}
__device__ __forceinline__ uint32_t pack4(const float* a, float s) {
    return f2fp8(s*a[0]) | (f2fp8(s*a[1])<<8) | (f2fp8(s*a[2])<<16) | (f2fp8(s*a[3])<<24);
}

// ---------------------------------------------------------------------------
// Prep. fp8 e4m3; args unscaled, D/E x16 (epilogue undoes). Two swizzles:
//  - car/cdr regions (Dl/Dr, args car/cdr): r18's 64B-window swizzle,
//    chunk c ^= ((m>>1)&3)  [proven at BK=64]
//  - cons regions (E, c12): NEW 128B-segment swizzle for BK=128,
//    chunk7 ^= (m&7) within each 128B segment (8 x 16B slots) — G4 recipe;
//    staging stays a linear copy, ds_read applies the same XOR.
// ---------------------------------------------------------------------------
__global__ __launch_bounds__(256) void k_prep(
    const float* __restrict__ x,
    const float* __restrict__ w0, const float* __restrict__ w1,
    const float* __restrict__ w2, const float* __restrict__ w3,
    const float* __restrict__ Dl, const float* __restrict__ Dr,
    const float* __restrict__ El, const float* __restrict__ Er,
    uint8_t* __restrict__ args8, uint8_t* __restrict__ dpad8,
    float* __restrict__ out)
{
    const int blk = blockIdx.x;
    const int t   = threadIdx.x;

    if (blk < 1024) {
        const int id = blk*256 + t;              // 0..262143
        const float* src; int n, c16, r0; size_t dst; int stride; bool consr;
        if (id < 131072) {
            const int mat = id >> 16;            // 0=Dl 1=Dr
            src = mat ? Dr : Dl;
            const int rem = id & 65535;
            n = rem >> 6; c16 = rem & 63; r0 = c16*16; stride = 1024;
            dst = (mat ? 1048576u : 0u); consr = false;
        } else {
            const int rem = id - 131072;
            n = rem >> 7; c16 = rem & 127;
            r0 = (c16 & 63)*16; stride = 2048;
            src = (c16 < 64) ? El : Er;
            dst = 2097152u; consr = true;
        }
        const int pos = consr
            ? ((c16 >> 3) << 7) + (((c16 & 7) ^ (n & 7)) << 4)
            : ((c16 >> 2) << 6) + (((c16 & 3) ^ ((n >> 1) & 3)) << 4);
        float v[16] = {};
        if (n < Rdim) {
            const float* sp = src + (size_t)n*Rdim + r0;
            if (r0 <= Rdim - 16) {
#pragma unroll
                for (int j = 0; j < 4; ++j) {
                    f32x4u u = *(const f32x4u*)(sp + j*4);
#pragma unroll
                    for (int q = 0; q < 4; ++q) v[j*4+q] = u[q];
                }
            } else {                              // r0 = 1008: 15 valid
#pragma unroll
                for (int j = 0; j < 3; ++j) {
                    f32x4u u = *(const f32x4u*)(sp + j*4);
#pragma unroll
                    for (int q = 0; q < 4; ++q) v[j*4+q] = u[q];
                }
                v[12] = sp[12]; v[13] = sp[13]; v[14] = sp[14];  // r=1023 pad
            }
        }
        uint32_t w[4];
#pragma unroll
        for (int j = 0; j < 4; ++j) w[j] = pack4(v + j*4, 16.f);
        *(uint4*)(dpad8 + dst + (size_t)n*stride + pos) =
            make_uint4(w[0], w[1], w[2], w[3]);
    } else if (blk < 5120) {
        const int m = blk - 1024;
        const int b = m >> 6;
        float wr0[16], wr1[16], wr2[16], wr3[16];
#pragma unroll
        for (int l = 0; l < 16; ++l) {
            wr0[l] = w0[b*16 + l]; wr1[l] = w1[b*16 + l];
            wr2[l] = w2[b*16 + l]; wr3[l] = w3[b*16 + l];
        }
        const float* xb = x + ((size_t)(b*16)*64 + (m & 63)) * (size_t)Rdim;
        float a0[4] = {}, a1[4] = {}, a2[4] = {}, a3[4] = {};
        if (t < 255) {
#pragma unroll
            for (int l = 0; l < 16; ++l) {
                f32x4u v = *(const f32x4u*)(xb + (size_t)l*(64*(size_t)Rdim) + t*4);
#pragma unroll
                for (int j = 0; j < 4; ++j) {
                    a0[j] += wr0[l]*v[j]; a1[j] += wr1[l]*v[j];
                    a2[j] += wr2[l]*v[j]; a3[j] += wr3[l]*v[j];
                }
            }
        } else {
#pragma unroll
            for (int l = 0; l < 16; ++l) {
                const float* p = xb + (size_t)l*(64*(size_t)Rdim) + 1020;
#pragma unroll
                for (int j = 0; j < 3; ++j) {
                    float v = p[j];
                    a0[j] += wr0[l]*v; a1[j] += wr1[l]*v;
                    a2[j] += wr2[l]*v; a3[j] += wr3[l]*v;
                }
            }
        }
        const int r0 = t*4;
        // car/cdr: 64B-window swizzle (r18)
        const int S2   = (m >> 1) & 3;
        const int posO = ((r0 >> 6) << 6) + ((((r0 >> 4) & 3) ^ S2) << 4) + (r0 & 15);
        // cons (c12): 128B-segment swizzle keyed (m&7)
        const int posC = (r0 & ~127) + ((((r0 >> 4) & 7) ^ (m & 7)) << 4) + (r0 & 15);
        *(uint32_t*)(args8 +            (size_t)m*1024 + posO) = pack4(a0, 1.f);
        *(uint32_t*)(args8 + 4194304 +  (size_t)m*1024 + posO) = pack4(a1, 1.f);
        uint8_t* c12 = args8 + 8388608 + (size_t)m*2048;
        *(uint32_t*)(c12 + posC)        = pack4(a2, 1.f);
        *(uint32_t*)(c12 + 1024 + posC) = pack4(a3, 1.f);
    } else {
        const int k = t >> 6, b2 = t & 63;
        const float* w = (k==0) ? w0 : (k==1) ? w1 : (k==2) ? w2 : w3;
        float s = 0.f, mx = -1e30f;
#pragma unroll
        for (int l = 0; l < 16; ++l) {
            float p = w[b2*16 + l];
            s += p * logf(p + 1e-12f);
            mx = fmaxf(mx, p);
        }
        out[3*(size_t)BFR +       k*64 + b2] = -s / logf(16.f);
        out[3*(size_t)BFR + 256 + k*64 + b2] = mx;
    }
}

// ---------------------------------------------------------------------------
// car/cdr GEMM tile — r18 verbatim (BM=256, BK=64 fp8, NKT=16, MI=8, JN=4).
// Triple-buffered, 1 barrier/kt, counted vmcnt(4).
// ---------------------------------------------------------------------------
__device__ __forceinline__ void gemm_cc(
    const uint8_t* __restrict__ Ab, const uint8_t* __restrict__ Bb,
    float* __restrict__ outp, char* lds, int mt, int nt)
{
    constexpr int AstB = 1024;
    const int tid  = threadIdx.x;
    const int wave = tid >> 6, lane = tid & 63;
    const int wm   = wave >> 2, wn = wave & 3; // 2M x 4N
    const int lr   = lane & 15, lk = lane >> 4;
    const int sw   = (lr >> 1) & 3;
    const int cb0 = ((((lk >> 1)    ) ^ sw) << 4) + ((lk & 1) << 3);
    const int cb1 = (((2 + (lk >> 1)) ^ sw) << 4) + ((lk & 1) << 3);

    const uint8_t* AgT = Ab + (size_t)(mt*256 + (tid>>2))*AstB + (tid&3)*16;
    const uint8_t* BgT = Bb + (size_t)(nt*256 + (tid>>2))*AstB + (tid&3)*16;

    f32x4 acc[8][4] = {};
    long af[8][2], bfr[4][2];

#define STG(bufidx, kt) do {                                                  \
    char* _a = lds + (bufidx)*16384 + wave*1024;                              \
    char* _b = lds + 49152 + (bufidx)*16384 + wave*1024;                      \
    const size_t _ko = (size_t)(kt)*64;                                      \
    _Pragma("unroll") for (int i = 0; i < 2; ++i)                             \
        async16(AgT + (size_t)(i*128)*AstB + _ko, _a + i*8192);               \
    _Pragma("unroll") for (int i = 0; i < 2; ++i)                             \
        async16(BgT + (size_t)(i*128)*AstB + _ko, _b + i*8192);               \
} while(0)

    STG(0, 0); STG(1, 1);
    asm volatile("s_waitcnt vmcnt(4)" ::: "memory");
    BAR();

    int cb = 0;
    for (int kt = 0; kt < 16; ++kt) {
        char* cA = lds + cb*16384;
        char* cB = lds + 49152 + cb*16384;
        int sb = cb + 2; if (sb >= 3) sb -= 3;
        const bool st = (kt + 2 < 16);
#pragma unroll
        for (int mi = 0; mi < 8; ++mi) {
            const char* rp = cA + (wm*128 + mi*16 + lr)*64;
            af[mi][0] = *(const long*)(rp + cb0);
            af[mi][1] = *(const long*)(rp + cb1);
        }
#pragma unroll
        for (int j = 0; j < 4; ++j) {
            const char* rp = cB + (wn*64 + j*16 + lr)*64;
            bfr[j][0] = *(const long*)(rp + cb0);
            bfr[j][1] = *(const long*)(rp + cb1);
        }
        if (st) STG(sb, kt+2);
        __builtin_amdgcn_s_setprio(1);
#pragma unroll
        for (int ks = 0; ks < 2; ++ks)
#pragma unroll
        for (int mi = 0; mi < 8; ++mi)
#pragma unroll
        for (int j = 0; j < 4; ++j)
            acc[mi][j] = __builtin_amdgcn_mfma_f32_16x16x32_fp8_fp8(
                af[mi][ks], bfr[j][ks], acc[mi][j], 0, 0, 0);
        __builtin_amdgcn_s_setprio(0);
        if (st)           { asm volatile("s_waitcnt vmcnt(4)" ::: "memory"); }
        else if (kt == 14){ asm volatile("s_waitcnt vmcnt(0)" ::: "memory"); }
        BAR();
        cb = cb + 1; if (cb == 3) cb = 0;
    }
#undef STG

#pragma unroll
    for (int mi = 0; mi < 8; ++mi) {
        const int gm0 = mt*256 + wm*128 + mi*16 + lk*4;
#pragma unroll
        for (int j = 0; j < 4; ++j) {
            const int gn = nt*256 + wn*64 + j*16 + lr;
            if (gn < Rdim) {
#pragma unroll
                for (int q = 0; q < 4; ++q)
                    outp[(size_t)(gm0 + q)*Rdim + gn] = acc[mi][j][q] * 0.0625f;
            }
        }
    }
}

// ---------------------------------------------------------------------------
// cons GEMM tile — NEW: BM=128 x BN=256, BK=128 fp8 -> NKT=16 (was 32; the
// per-iteration convoy overhead halves and per-kt MFMA matches car: 64).
// LDS: A 3x16KB @0, B 3x32KB @49152 = 144 KiB. U=6 units/kt, vmcnt(6).
// 128B-row reads use chunk7 ^ (row&7) swizzle (2 lanes/bank = free).
// Epilogue adds root_filler x root_role and undoes the x16 D/E scale.
// ---------------------------------------------------------------------------
__device__ __forceinline__ void gemm_cons(
    const uint8_t* __restrict__ Ab, const uint8_t* __restrict__ Bb,
    const float* __restrict__ rf, const float* __restrict__ rr,
    float* __restrict__ outp, char* lds, int mt, int nt)
{
    const int tid  = threadIdx.x;
    const int wave = tid >> 6, lane = tid & 63;
    const int wm   = wave >> 2, wn = wave & 3; // 2M x 4N
    const int lr   = lane & 15, lk = lane >> 4;
    int cbs[4];
#pragma unroll
    for (int ks = 0; ks < 4; ++ks)
        cbs[ks] = (((ks*2 + (lk >> 1)) ^ (lr & 7)) << 4) + ((lk & 1) << 3);

    const uint8_t* AgT = Ab + (size_t)(mt*128 + (tid>>3))*2048 + (tid&7)*16;
    const uint8_t* BgT = Bb + (size_t)(nt*256 + (tid>>3))*2048 + (tid&7)*16;

    f32x4 acc[4][4] = {};
    long af[4][4], bfr[4][4];

#define STGC(bufidx, kt) do {                                                 \
    char* _a = lds + (bufidx)*16384 + wave*1024;                              \
    char* _b = lds + 49152 + (bufidx)*32768 + wave*1024;                      \
    const size_t _ko = (size_t)(kt)*128;                                      \
    async16(AgT + _ko, _a);                                                   \
    async16(AgT + (size_t)64*2048 + _ko, _a + 8192);                          \
    _Pragma("unroll") for (int i = 0; i < 4; ++i)                             \
        async16(BgT + (size_t)(i*64)*2048 + _ko, _b + i*8192);                \
} while(0)

    STGC(0, 0); STGC(1, 1);
    asm volatile("s_waitcnt vmcnt(6)" ::: "memory");
    BAR();

    int cb = 0;
    for (int kt = 0; kt < 16; ++kt) {
        char* cA = lds + cb*16384;
        char* cB = lds + 49152 + cb*32768;
        int sb = cb + 2; if (sb >= 3) sb -= 3;
        const bool st = (kt + 2 < 16);
#pragma unroll
        for (int mi = 0; mi < 4; ++mi) {
            const char* rp = cA + (wm*64 + mi*16 + lr)*128;
#pragma unroll
            for (int ks = 0; ks < 4; ++ks)
                af[mi][ks] = *(const long*)(rp + cbs[ks]);
        }
#pragma unroll
        for (int j = 0; j < 4; ++j) {
            const char* rp = cB + (wn*64 + j*16 + lr)*128;
#pragma unroll
            for (int ks = 0; ks < 4; ++ks)
                bfr[j][ks] = *(const long*)(rp + cbs[ks]);
        }
        if (st) STGC(sb, kt+2);
        __builtin_amdgcn_s_setprio(1);
#pragma unroll
        for (int ks = 0; ks < 4; ++ks)
#pragma unroll
        for (int mi = 0; mi < 4; ++mi)
#pragma unroll
        for (int j = 0; j < 4; ++j)
            acc[mi][j] = __builtin_amdgcn_mfma_f32_16x16x32_fp8_fp8(
                af[mi][ks], bfr[j][ks], acc[mi][j], 0, 0, 0);
        __builtin_amdgcn_s_setprio(0);
        if (st)           { asm volatile("s_waitcnt vmcnt(6)" ::: "memory"); }
        else if (kt == 14){ asm volatile("s_waitcnt vmcnt(0)" ::: "memory"); }
        BAR();
        cb = cb + 1; if (cb == 3) cb = 0;
    }
#undef STGC

#pragma unroll
    for (int mi = 0; mi < 4; ++mi) {
        const int gm0 = mt*128 + wm*64 + mi*16 + lk*4;
#pragma unroll
        for (int j = 0; j < 4; ++j) {
            const int gn = nt*256 + wn*64 + j*16 + lr;
            if (gn < Rdim) {
                const float rv = rr[gn];
#pragma unroll
                for (int q = 0; q < 4; ++q) {
                    float v = acc[mi][j][q] * 0.0625f + rf[gm0 + q] * rv;
                    outp[(size_t)(gm0 + q)*Rdim + gn] = v;
                }
            }
        }
    }
}

// 256 blocks, ALL 16 uniform-work iterations: per XCD 16 cons (128x256,
// BK=128, K=2048) + 8 car + 8 cdr (256x256, BK=64, K=1024).
__global__ __launch_bounds__(512, 1) void k_gemm(
    const uint8_t* __restrict__ args8, const uint8_t* __restrict__ dpad8,
    const float* __restrict__ root_filler, const float* __restrict__ root_role,
    float* __restrict__ out)
{
    __shared__ char lds[147456];      // 144 KiB (cons); car/cdr use 96 KiB
    const int bid = blockIdx.x;
    const int xcd = bid & 7, idx = bid >> 3;   // idx 0..31

    if (idx < 16) {
        const int tile = xcd*16 + idx;         // 0..127: mt 0..31, nt 0..3
        gemm_cons(args8 + 8388608, dpad8 + 2097152,
            root_filler, root_role, out + 2*(size_t)BFR, lds, tile >> 2, tile & 3);
    } else if (idx < 24) {
        const int tile = xcd*8 + idx - 16;     // 0..63: mt 0..15, nt 0..3
        gemm_cc(args8, dpad8, out, lds, tile >> 2, tile & 3);
    } else {
        const int tile = xcd*8 + idx - 24;
        gemm_cc(args8 + 4194304, dpad8 + 1048576,
            out + (size_t)BFR, lds, tile >> 2, tile & 3);
    }
}

// ---------------------------------------------------------------------------
extern "C" void kernel_launch(void* const* d_in, const int* in_sizes, int n_in,
                              void* d_out, int out_size, void* d_ws, size_t ws_size,
                              hipStream_t stream)
{
    const float* x           = (const float*)d_in[0];
    const float* car_w       = (const float*)d_in[1];
    const float* cdr_w       = (const float*)d_in[2];
    const float* cons1_w     = (const float*)d_in[3];
    const float* cons2_w     = (const float*)d_in[4];
    const float* root_filler = (const float*)d_in[5];
    const float* Dl          = (const float*)d_in[6];
    const float* Dr          = (const float*)d_in[7];
    const float* El          = (const float*)d_in[8];
    const float* Er          = (const float*)d_in[9];
    const float* root_role   = (const float*)d_in[10];
    float* out = (float*)d_out;

    uint8_t* args8 = (uint8_t*)d_ws;              // 16.8 MB
    uint8_t* dpad8 = args8 + 16777216;            //  4.2 MB

    k_prep<<<dim3(5121), dim3(256), 0, stream>>>(
        x, car_w, cdr_w, cons1_w, cons2_w, Dl, Dr, El, Er, args8, dpad8, out);
    k_gemm<<<dim3(256),  dim3(512), 0, stream>>>(
        args8, dpad8, root_filler, root_role, out);
}

// Round 23
// 100.699 us; speedup vs baseline: 1.1136x; 1.0007x over previous
//
#include <hip/hip_runtime.h>
#include <hip/hip_bf16.h>
#include <hip/hip_fp8.h>
#include <stdint.h>

#define Rdim 1023
#define BFR  4190208           // 64*64*1023

typedef float  f32x4  __attribute__((ext_vector_type(4)));
typedef float  f32x4u __attribute__((ext_vector_type(4), aligned(4)));

__device__ __forceinline__ void async16(const void* g, void* l) {
    __builtin_amdgcn_global_load_lds(
        (const __attribute__((address_space(1))) void*)g,
        (__attribute__((address_space(3))) void*)l, 16, 0, 0);
}

#define BAR()  do { __builtin_amdgcn_s_barrier(); __builtin_amdgcn_sched_barrier(0); } while(0)

__device__ __forceinline__ uint32_t f2fp8(float f) {
    __hip_fp8_e4m3 v(f);
    return (uint32_t)v.__x;
}
__device__ __forceinline__ uint32_t pack4(const float* a, float s) {
    return f2fp8(s*a[0]) | (f2fp8(s*a[1])<<8) | (f2fp8(s*a[2])<<16) | (f2fp8(s*a[3])<<24);
}

// ---------------------------------------------------------------------------
// Prep (r21 verbatim — session best). fp8 e4m3; args unscaled, D/E x16
// (epilogue undoes). Two swizzles:
//  - car/cdr regions (Dl/Dr, args car/cdr): 64B-window swizzle,
//    chunk c ^= ((m>>1)&3)  [proven at BK=64]
//  - cons regions (E, c12): 128B-segment swizzle for BK=128,
//    chunk7 ^= (m&7) within each 128B segment; staging stays a linear copy.
// ---------------------------------------------------------------------------
__global__ __launch_bounds__(256) void k_prep(
    const float* __restrict__ x,
    const float* __restrict__ w0, const float* __restrict__ w1,
    const float* __restrict__ w2, const float* __restrict__ w3,
    const float* __restrict__ Dl, const float* __restrict__ Dr,
    const float* __restrict__ El, const float* __restrict__ Er,
    uint8_t* __restrict__ args8, uint8_t* __restrict__ dpad8,
    float* __restrict__ out)
{
    const int blk = blockIdx.x;
    const int t   = threadIdx.x;

    if (blk < 1024) {
        const int id = blk*256 + t;              // 0..262143
        const float* src; int n, c16, r0; size_t dst; int stride; bool consr;
        if (id < 131072) {
            const int mat = id >> 16;            // 0=Dl 1=Dr
            src = mat ? Dr : Dl;
            const int rem = id & 65535;
            n = rem >> 6; c16 = rem & 63; r0 = c16*16; stride = 1024;
            dst = (mat ? 1048576u : 0u); consr = false;
        } else {
            const int rem = id - 131072;
            n = rem >> 7; c16 = rem & 127;
            r0 = (c16 & 63)*16; stride = 2048;
            src = (c16 < 64) ? El : Er;
            dst = 2097152u; consr = true;
        }
        const int pos = consr
            ? ((c16 >> 3) << 7) + (((c16 & 7) ^ (n & 7)) << 4)
            : ((c16 >> 2) << 6) + (((c16 & 3) ^ ((n >> 1) & 3)) << 4);
        float v[16] = {};
        if (n < Rdim) {
            const float* sp = src + (size_t)n*Rdim + r0;
            if (r0 <= Rdim - 16) {
#pragma unroll
                for (int j = 0; j < 4; ++j) {
                    f32x4u u = *(const f32x4u*)(sp + j*4);
#pragma unroll
                    for (int q = 0; q < 4; ++q) v[j*4+q] = u[q];
                }
            } else {                              // r0 = 1008: 15 valid
#pragma unroll
                for (int j = 0; j < 3; ++j) {
                    f32x4u u = *(const f32x4u*)(sp + j*4);
#pragma unroll
                    for (int q = 0; q < 4; ++q) v[j*4+q] = u[q];
                }
                v[12] = sp[12]; v[13] = sp[13]; v[14] = sp[14];  // r=1023 pad
            }
        }
        uint32_t w[4];
#pragma unroll
        for (int j = 0; j < 4; ++j) w[j] = pack4(v + j*4, 16.f);
        *(uint4*)(dpad8 + dst + (size_t)n*stride + pos) =
            make_uint4(w[0], w[1], w[2], w[3]);
    } else if (blk < 5120) {
        const int m = blk - 1024;
        const int b = m >> 6;
        float wr0[16], wr1[16], wr2[16], wr3[16];
#pragma unroll
        for (int l = 0; l < 16; ++l) {
            wr0[l] = w0[b*16 + l]; wr1[l] = w1[b*16 + l];
            wr2[l] = w2[b*16 + l]; wr3[l] = w3[b*16 + l];
        }
        const float* xb = x + ((size_t)(b*16)*64 + (m & 63)) * (size_t)Rdim;
        float a0[4] = {}, a1[4] = {}, a2[4] = {}, a3[4] = {};
        if (t < 255) {
#pragma unroll
            for (int l = 0; l < 16; ++l) {
                f32x4u v = *(const f32x4u*)(xb + (size_t)l*(64*(size_t)Rdim) + t*4);
#pragma unroll
                for (int j = 0; j < 4; ++j) {
                    a0[j] += wr0[l]*v[j]; a1[j] += wr1[l]*v[j];
                    a2[j] += wr2[l]*v[j]; a3[j] += wr3[l]*v[j];
                }
            }
        } else {
#pragma unroll
            for (int l = 0; l < 16; ++l) {
                const float* p = xb + (size_t)l*(64*(size_t)Rdim) + 1020;
#pragma unroll
                for (int j = 0; j < 3; ++j) {
                    float v = p[j];
                    a0[j] += wr0[l]*v; a1[j] += wr1[l]*v;
                    a2[j] += wr2[l]*v; a3[j] += wr3[l]*v;
                }
            }
        }
        const int r0 = t*4;
        // car/cdr: 64B-window swizzle
        const int S2   = (m >> 1) & 3;
        const int posO = ((r0 >> 6) << 6) + ((((r0 >> 4) & 3) ^ S2) << 4) + (r0 & 15);
        // cons (c12): 128B-segment swizzle keyed (m&7)
        const int posC = (r0 & ~127) + ((((r0 >> 4) & 7) ^ (m & 7)) << 4) + (r0 & 15);
        *(uint32_t*)(args8 +            (size_t)m*1024 + posO) = pack4(a0, 1.f);
        *(uint32_t*)(args8 + 4194304 +  (size_t)m*1024 + posO) = pack4(a1, 1.f);
        uint8_t* c12 = args8 + 8388608 + (size_t)m*2048;
        *(uint32_t*)(c12 + posC)        = pack4(a2, 1.f);
        *(uint32_t*)(c12 + 1024 + posC) = pack4(a3, 1.f);
    } else {
        const int k = t >> 6, b2 = t & 63;
        const float* w = (k==0) ? w0 : (k==1) ? w1 : (k==2) ? w2 : w3;
        float s = 0.f, mx = -1e30f;
#pragma unroll
        for (int l = 0; l < 16; ++l) {
            float p = w[b2*16 + l];
            s += p * logf(p + 1e-12f);
            mx = fmaxf(mx, p);
        }
        out[3*(size_t)BFR +       k*64 + b2] = -s / logf(16.f);
        out[3*(size_t)BFR + 256 + k*64 + b2] = mx;
    }
}

// ---------------------------------------------------------------------------
// car/cdr GEMM tile — BM=256, BK=64 fp8, NKT=16, MI=8, JN=4.
// Triple-buffered, 1 barrier/kt, counted vmcnt(4).
// ---------------------------------------------------------------------------
__device__ __forceinline__ void gemm_cc(
    const uint8_t* __restrict__ Ab, const uint8_t* __restrict__ Bb,
    float* __restrict__ outp, char* lds, int mt, int nt)
{
    constexpr int AstB = 1024;
    const int tid  = threadIdx.x;
    const int wave = tid >> 6, lane = tid & 63;
    const int wm   = wave >> 2, wn = wave & 3; // 2M x 4N
    const int lr   = lane & 15, lk = lane >> 4;
    const int sw   = (lr >> 1) & 3;
    const int cb0 = ((((lk >> 1)    ) ^ sw) << 4) + ((lk & 1) << 3);
    const int cb1 = (((2 + (lk >> 1)) ^ sw) << 4) + ((lk & 1) << 3);

    const uint8_t* AgT = Ab + (size_t)(mt*256 + (tid>>2))*AstB + (tid&3)*16;
    const uint8_t* BgT = Bb + (size_t)(nt*256 + (tid>>2))*AstB + (tid&3)*16;

    f32x4 acc[8][4] = {};
    long af[8][2], bfr[4][2];

#define STG(bufidx, kt) do {                                                  \
    char* _a = lds + (bufidx)*16384 + wave*1024;                              \
    char* _b = lds + 49152 + (bufidx)*16384 + wave*1024;                      \
    const size_t _ko = (size_t)(kt)*64;                                      \
    _Pragma("unroll") for (int i = 0; i < 2; ++i)                             \
        async16(AgT + (size_t)(i*128)*AstB + _ko, _a + i*8192);               \
    _Pragma("unroll") for (int i = 0; i < 2; ++i)                             \
        async16(BgT + (size_t)(i*128)*AstB + _ko, _b + i*8192);               \
} while(0)

    STG(0, 0); STG(1, 1);
    asm volatile("s_waitcnt vmcnt(4)" ::: "memory");
    BAR();

    int cb = 0;
    for (int kt = 0; kt < 16; ++kt) {
        char* cA = lds + cb*16384;
        char* cB = lds + 49152 + cb*16384;
        int sb = cb + 2; if (sb >= 3) sb -= 3;
        const bool st = (kt + 2 < 16);
#pragma unroll
        for (int mi = 0; mi < 8; ++mi) {
            const char* rp = cA + (wm*128 + mi*16 + lr)*64;
            af[mi][0] = *(const long*)(rp + cb0);
            af[mi][1] = *(const long*)(rp + cb1);
        }
#pragma unroll
        for (int j = 0; j < 4; ++j) {
            const char* rp = cB + (wn*64 + j*16 + lr)*64;
            bfr[j][0] = *(const long*)(rp + cb0);
            bfr[j][1] = *(const long*)(rp + cb1);
        }
        if (st) STG(sb, kt+2);
        __builtin_amdgcn_s_setprio(1);
#pragma unroll
        for (int ks = 0; ks < 2; ++ks)
#pragma unroll
        for (int mi = 0; mi < 8; ++mi)
#pragma unroll
        for (int j = 0; j < 4; ++j)
            acc[mi][j] = __builtin_amdgcn_mfma_f32_16x16x32_fp8_fp8(
                af[mi][ks], bfr[j][ks], acc[mi][j], 0, 0, 0);
        __builtin_amdgcn_s_setprio(0);
        if (st)           { asm volatile("s_waitcnt vmcnt(4)" ::: "memory"); }
        else if (kt == 14){ asm volatile("s_waitcnt vmcnt(0)" ::: "memory"); }
        BAR();
        cb = cb + 1; if (cb == 3) cb = 0;
    }
#undef STG

#pragma unroll
    for (int mi = 0; mi < 8; ++mi) {
        const int gm0 = mt*256 + wm*128 + mi*16 + lk*4;
#pragma unroll
        for (int j = 0; j < 4; ++j) {
            const int gn = nt*256 + wn*64 + j*16 + lr;
            if (gn < Rdim) {
#pragma unroll
                for (int q = 0; q < 4; ++q)
                    outp[(size_t)(gm0 + q)*Rdim + gn] = acc[mi][j][q] * 0.0625f;
            }
        }
    }
}

// ---------------------------------------------------------------------------
// cons GEMM tile — BM=128 x BN=256, BK=128 fp8 -> NKT=16; per-kt MFMA = 64
// (matches car). LDS: A 3x16KB @0, B 3x32KB @49152 = 144 KiB. U=6/kt,
// vmcnt(6). 128B-row reads use chunk7 ^ (row&7) swizzle (2 lanes/bank).
// Epilogue adds root_filler x root_role and undoes the x16 D/E scale.
// ---------------------------------------------------------------------------
__device__ __forceinline__ void gemm_cons(
    const uint8_t* __restrict__ Ab, const uint8_t* __restrict__ Bb,
    const float* __restrict__ rf, const float* __restrict__ rr,
    float* __restrict__ outp, char* lds, int mt, int nt)
{
    const int tid  = threadIdx.x;
    const int wave = tid >> 6, lane = tid & 63;
    const int wm   = wave >> 2, wn = wave & 3; // 2M x 4N
    const int lr   = lane & 15, lk = lane >> 4;
    int cbs[4];
#pragma unroll
    for (int ks = 0; ks < 4; ++ks)
        cbs[ks] = (((ks*2 + (lk >> 1)) ^ (lr & 7)) << 4) + ((lk & 1) << 3);

    const uint8_t* AgT = Ab + (size_t)(mt*128 + (tid>>3))*2048 + (tid&7)*16;
    const uint8_t* BgT = Bb + (size_t)(nt*256 + (tid>>3))*2048 + (tid&7)*16;

    f32x4 acc[4][4] = {};
    long af[4][4], bfr[4][4];

#define STGC(bufidx, kt) do {                                                 \
    char* _a = lds + (bufidx)*16384 + wave*1024;                              \
    char* _b = lds + 49152 + (bufidx)*32768 + wave*1024;                      \
    const size_t _ko = (size_t)(kt)*128;                                      \
    async16(AgT + _ko, _a);                                                   \
    async16(AgT + (size_t)64*2048 + _ko, _a + 8192);                          \
    _Pragma("unroll") for (int i = 0; i < 4; ++i)                             \
        async16(BgT + (size_t)(i*64)*2048 + _ko, _b + i*8192);                \
} while(0)

    STGC(0, 0); STGC(1, 1);
    asm volatile("s_waitcnt vmcnt(6)" ::: "memory");
    BAR();

    int cb = 0;
    for (int kt = 0; kt < 16; ++kt) {
        char* cA = lds + cb*16384;
        char* cB = lds + 49152 + cb*32768;
        int sb = cb + 2; if (sb >= 3) sb -= 3;
        const bool st = (kt + 2 < 16);
#pragma unroll
        for (int mi = 0; mi < 4; ++mi) {
            const char* rp = cA + (wm*64 + mi*16 + lr)*128;
#pragma unroll
            for (int ks = 0; ks < 4; ++ks)
                af[mi][ks] = *(const long*)(rp + cbs[ks]);
        }
#pragma unroll
        for (int j = 0; j < 4; ++j) {
            const char* rp = cB + (wn*64 + j*16 + lr)*128;
#pragma unroll
            for (int ks = 0; ks < 4; ++ks)
                bfr[j][ks] = *(const long*)(rp + cbs[ks]);
        }
        if (st) STGC(sb, kt+2);
        __builtin_amdgcn_s_setprio(1);
#pragma unroll
        for (int ks = 0; ks < 4; ++ks)
#pragma unroll
        for (int mi = 0; mi < 4; ++mi)
#pragma unroll
        for (int j = 0; j < 4; ++j)
            acc[mi][j] = __builtin_amdgcn_mfma_f32_16x16x32_fp8_fp8(
                af[mi][ks], bfr[j][ks], acc[mi][j], 0, 0, 0);
        __builtin_amdgcn_s_setprio(0);
        if (st)           { asm volatile("s_waitcnt vmcnt(6)" ::: "memory"); }
        else if (kt == 14){ asm volatile("s_waitcnt vmcnt(0)" ::: "memory"); }
        BAR();
        cb = cb + 1; if (cb == 3) cb = 0;
    }
#undef STGC

#pragma unroll
    for (int mi = 0; mi < 4; ++mi) {
        const int gm0 = mt*128 + wm*64 + mi*16 + lk*4;
#pragma unroll
        for (int j = 0; j < 4; ++j) {
            const int gn = nt*256 + wn*64 + j*16 + lr;
            if (gn < Rdim) {
                const float rv = rr[gn];
#pragma unroll
                for (int q = 0; q < 4; ++q) {
                    float v = acc[mi][j][q] * 0.0625f + rf[gm0 + q] * rv;
                    outp[(size_t)(gm0 + q)*Rdim + gn] = v;
                }
            }
        }
    }
}

// 256 blocks, ALL 16 uniform-work iterations: per XCD 16 cons (128x256,
// BK=128, K=2048) + 8 car + 8 cdr (256x256, BK=64, K=1024).
__global__ __launch_bounds__(512, 1) void k_gemm(
    const uint8_t* __restrict__ args8, const uint8_t* __restrict__ dpad8,
    const float* __restrict__ root_filler, const float* __restrict__ root_role,
    float* __restrict__ out)
{
    __shared__ char lds[147456];      // 144 KiB (cons); car/cdr use 96 KiB
    const int bid = blockIdx.x;
    const int xcd = bid & 7, idx = bid >> 3;   // idx 0..31

    if (idx < 16) {
        const int tile = xcd*16 + idx;         // 0..127: mt 0..31, nt 0..3
        gemm_cons(args8 + 8388608, dpad8 + 2097152,
            root_filler, root_role, out + 2*(size_t)BFR, lds, tile >> 2, tile & 3);
    } else if (idx < 24) {
        const int tile = xcd*8 + idx - 16;     // 0..63: mt 0..15, nt 0..3
        gemm_cc(args8, dpad8, out, lds, tile >> 2, tile & 3);
    } else {
        const int tile = xcd*8 + idx - 24;
        gemm_cc(args8 + 4194304, dpad8 + 1048576,
            out + (size_t)BFR, lds, tile >> 2, tile & 3);
    }
}

// ---------------------------------------------------------------------------
extern "C" void kernel_launch(void* const* d_in, const int* in_sizes, int n_in,
                              void* d_out, int out_size, void* d_ws, size_t ws_size,
                              hipStream_t stream)
{
    const float* x           = (const float*)d_in[0];
    const float* car_w       = (const float*)d_in[1];
    const float* cdr_w       = (const float*)d_in[2];
    const float* cons1_w     = (const float*)d_in[3];
    const float* cons2_w     = (const float*)d_in[4];
    const float* root_filler = (const float*)d_in[5];
    const float* Dl          = (const float*)d_in[6];
    const float* Dr          = (const float*)d_in[7];
    const float* El          = (const float*)d_in[8];
    const float* Er          = (const float*)d_in[9];
    const float* root_role   = (const float*)d_in[10];
    float* out = (float*)d_out;

    uint8_t* args8 = (uint8_t*)d_ws;              // 16.8 MB
    uint8_t* dpad8 = args8 + 16777216;            //  4.2 MB

    k_prep<<<dim3(5121), dim3(256), 0, stream>>>(
        x, car_w, cdr_w, cons1_w, cons2_w, Dl, Dr, El, Er, args8, dpad8, out);
    k_gemm<<<dim3(256),  dim3(512), 0, stream>>>(
        args8, dpad8, root_filler, root_role, out);
}